// Round 8
// baseline (69.382 us; speedup 1.0000x reference)
//
#include <hip/hip_runtime.h>

#define IMG 192
// fused-XY geometry (scale0 only): TX=8, TXP=9 (odd: bank spread), SPAN=44,
// CHUNK=32, NT=8 tiles, grid = 192*8.
// B2: [5][z=192][oy=57][60] = 3,283,200 fl (13.1 MB)
// B3: [5][oz=57][oy=57][60] =   974,700 fl (3.9 MB)

// ---------------------------------------------------------------------------
// Fused x+y pass, scale 0 only. Block = (z, ox-tile of 8).
// Stages raw input rows (CHUNK at a time) in LDS, x-box-sums into
// sx[5][192][9], then y-box-sums from sx -> B2 directly. No B1.
// ---------------------------------------------------------------------------
__global__ __launch_bounds__(256) void fuseXY_s0(
    const float* __restrict__ I, const float* __restrict__ T,
    float* __restrict__ B2)
{
    constexpr int TX = 8, TXP = 9, SPAN = 44, CHUNK = 32, NT = 8;
    constexpr int SPV = SPAN / 4;            // 11 float4
    __shared__ __align__(16) float rawI[CHUNK][SPAN];
    __shared__ __align__(16) float rawT[CHUNK][SPAN];
    __shared__ float sx[5][IMG][TXP];

    const int tid  = threadIdx.x;
    const int z    = blockIdx.x / NT;
    const int tile = blockIdx.x - z * NT;
    const int ox0  = tile * TX;
    const int TXe  = (57 - ox0 < TX) ? (57 - ox0) : TX;   // 8, last tile 1
    const int gx0  = (ox0 * 3) >> 2;         // float4 index of window start

    const float4* Iv = (const float4*)I;
    const float4* Tv = (const float4*)T;

    for (int ch = 0; ch < IMG / CHUNK; ++ch) {
        // ---- stage CHUNK rows of the x-window (coalesced float4) ----
        const size_t rowbase = ((size_t)z * IMG + ch * CHUNK) * (IMG / 4);
        for (int t = tid; t < CHUNK * SPV; t += 256) {
            int r = t / SPV, v = t - r * SPV;
            int gx = gx0 + v;
            float4 a = make_float4(0.f, 0.f, 0.f, 0.f), b = a;
            if (gx < IMG / 4) {
                a = Iv[rowbase + (size_t)r * (IMG / 4) + gx];
                b = Tv[rowbase + (size_t)r * (IMG / 4) + gx];
            }
            ((float4*)&rawI[r][0])[v] = a;
            ((float4*)&rawT[r][0])[v] = b;
        }
        __syncthreads();
        // ---- x-box-sums for these rows (1 item/thread) ----
        {
            int r  = tid >> 3;           // 0..31
            int tx = tid & 7;
            const float* a = &rawI[r][tx * 3];
            const float* b = &rawT[r][tx * 3];
            float sI = 0.f, sT = 0.f, sI2 = 0.f, sT2 = 0.f, sIT = 0.f;
#pragma unroll
            for (int i = 0; i < 12; ++i) {
                float x = a[2 * i], y = b[2 * i];
                sI += x; sT += y; sI2 += x * x; sT2 += y * y; sIT += x * y;
            }
            int y = ch * CHUNK + r;
            sx[0][y][tx] = sI;
            sx[1][y][tx] = sT;
            sx[2][y][tx] = sI2;
            sx[3][y][tx] = sT2;
            sx[4][y][tx] = sIT;
        }
        __syncthreads();
    }

    // ---- y-box-sums from sx, write B2 ----
    for (int t = tid; t < 5 * 57 * TX; t += 256) {
        int tx = t & 7;
        int q  = t >> 3;                 // c*57 + oy
        int oy = q % 57;
        int c  = q / 57;
        if (tx < TXe) {
            float acc = 0.f;
#pragma unroll
            for (int j = 0; j < 12; ++j) acc += sx[c][oy * 3 + 2 * j][tx];
            B2[(size_t)c * (IMG * 57 * 60) + ((size_t)z * 57 + oy) * 60
               + ox0 + tx] = acc;
        }
    }
}

// ---------------------------------------------------------------------------
// Pass 3 (z), scale0, float4: B2[c][3oz+2l][oy][60] -> B3[c][oz][oy][60].
// ---------------------------------------------------------------------------
__global__ __launch_bounds__(256) void passZ_s0(
    const float* __restrict__ B2, float4* __restrict__ B3)
{
    constexpr int POV = 15;
    constexpr int CV  = IMG * 57 * POV;
    constexpr int N3V = 57 * 57 * POV;      // 48735 float4 per channel
    int idx = blockIdx.x * 256 + threadIdx.x;
    if (idx >= 5 * N3V) return;
    int c   = idx / N3V;
    int rv  = idx - c * N3V;
    int ox4 = rv % POV;
    int t   = rv / POV;
    int oy  = t % 57;
    int oz  = t / 57;
    const float4* p = (const float4*)B2 + (size_t)c * CV
                      + (size_t)(oz * 3) * 57 * POV + (size_t)oy * POV + ox4;
    float4 acc = make_float4(0.f, 0.f, 0.f, 0.f);
#pragma unroll
    for (int l = 0; l < 12; ++l) {
        float4 v = p[(size_t)l * 2 * 57 * POV];
        acc.x += v.x; acc.y += v.y; acc.z += v.z; acc.w += v.w;
    }
    B3[idx] = acc;
}

// ---------------------------------------------------------------------------
// LNCC helpers + scale-1/2 derivation from B3 (exact window decomposition).
// ---------------------------------------------------------------------------
__device__ __forceinline__ float lncc1(float i_s, float t_s, float i2, float t2,
                                       float it, float inv_numel) {
    float cross = it - i_s * t_s * inv_numel;
    float iv    = i2 - i_s * i_s * inv_numel;
    float tv    = t2 - t_s * t_s * inv_numel;
    return cross * cross / (iv * tv + 1e-5f);
}

__device__ __forceinline__ float red_s0(const float* __restrict__ B3, int rv,
                                        float inv_numel, float wdiv) {
    constexpr int POV = 15;
    constexpr int N3V = 57 * 57 * POV;
    const float4* p = (const float4*)B3;
    float4 s0 = p[rv];
    float4 s1 = p[(size_t)1 * N3V + rv];
    float4 s2 = p[(size_t)2 * N3V + rv];
    float4 s3 = p[(size_t)3 * N3V + rv];
    float4 s4 = p[(size_t)4 * N3V + rv];
    int ox = (rv % POV) * 4;
    float local = 0.f;
    if (ox + 0 < 57) local += lncc1(s0.x, s1.x, s2.x, s3.x, s4.x, inv_numel);
    if (ox + 1 < 57) local += lncc1(s0.y, s1.y, s2.y, s3.y, s4.y, inv_numel);
    if (ox + 2 < 57) local += lncc1(s0.z, s1.z, s2.z, s3.z, s4.z, inv_numel);
    if (ox + 3 < 57) local += lncc1(s0.w, s1.w, s2.w, s3.w, s4.w, inv_numel);
    return local * wdiv;
}

template<int DN, int M>
__device__ __forceinline__ float derive_lncc(const float* __restrict__ B3,
                                             int r, int O1,
                                             float inv_numel, float wdiv) {
    int ox = r % O1;
    int t  = r / O1;
    int oy = t % O1;
    int oz = t / O1;
    float s[5];
    for (int c = 0; c < 5; ++c) {
        float acc = 0.f;
        for (int iz = 0; iz < DN; ++iz)
            for (int iy = 0; iy < DN; ++iy) {
                const float* p = B3
                    + (((size_t)c * 57 + (M * oz + 8 * iz)) * 57
                       + (M * oy + 8 * iy)) * 60 + M * ox;
#pragma unroll
                for (int ix = 0; ix < DN; ++ix) acc += p[8 * ix];
            }
        s[c] = acc;
    }
    return wdiv * lncc1(s[0], s[1], s[2], s[3], s[4], inv_numel);
}

__global__ __launch_bounds__(256) void reduce_all(
    const float* __restrict__ B3, float* __restrict__ partials)
{
    const int b = blockIdx.x;
    float v = 0.f;
    if (b < 191) {                                   // scale0: 48735 float4
        int r = b * 256 + threadIdx.x;
        if (r < 48735) v = red_s0(B3, r, 1.f / 1728.f, 0.1f / 185193.f);
    } else if (b < 253) {                            // scale1: 15625 outputs
        int r = (b - 191) * 256 + threadIdx.x;
        if (r < 15625)
            v = derive_lncc<2, 2>(B3, r, 25, 1.f / 13824.f, 0.3f / 15625.f);
    } else {                                         // scale2: 729 outputs
        int r = (b - 253) * 256 + threadIdx.x;
        if (r < 729)
            v = derive_lncc<4, 4>(B3, r, 9, 1.f / 110592.f, 0.6f / 729.f);
    }
    __shared__ float red[256];
    red[threadIdx.x] = v;
    __syncthreads();
    for (int o = 128; o > 0; o >>= 1) {
        if (threadIdx.x < o) red[threadIdx.x] += red[threadIdx.x + o];
        __syncthreads();
    }
    if (threadIdx.x == 0) partials[blockIdx.x] = red[0];
}

__global__ __launch_bounds__(256) void finalize_n(
    const float* __restrict__ partials, int n, float* __restrict__ out)
{
    float v = 0.f;
    for (int i = threadIdx.x; i < n; i += 256) v += partials[i];
    __shared__ float red[256];
    red[threadIdx.x] = v;
    __syncthreads();
    for (int o = 128; o > 0; o >>= 1) {
        if (threadIdx.x < o) red[threadIdx.x] += red[threadIdx.x + o];
        __syncthreads();
    }
    if (threadIdx.x == 0) out[0] = 1.0f - red[0];
}

// ------------------- fallback kernels (small-ws path) ----------------------
__global__ void pass1_one(const float* __restrict__ I, const float* __restrict__ T,
                          float* __restrict__ B1, int O, int s, int k, int c) {
    int idx = blockIdx.x * blockDim.x + threadIdx.x;
    if (idx >= IMG * IMG * O) return;
    int ox = idx % O;
    int zy = idx / O;
    const float* pI = I + (size_t)zy * IMG + ox * s;
    const float* pT = T + (size_t)zy * IMG + ox * s;
    float acc = 0.f;
    for (int i = 0; i < k; ++i) {
        float v;
        if (c == 0)      v = pI[2 * i];
        else if (c == 1) v = pT[2 * i];
        else if (c == 2) { float a = pI[2 * i]; v = a * a; }
        else if (c == 3) { float bb = pT[2 * i]; v = bb * bb; }
        else             { v = pI[2 * i] * pT[2 * i]; }
        acc += v;
    }
    B1[idx] = acc;
}

__global__ void pass_y(const float* __restrict__ Bin, float* __restrict__ Bout,
                       int O, int s, int k, int n1, int n2) {
    int idx = blockIdx.x * blockDim.x + threadIdx.x;
    if (idx >= n2) return;
    int ox = idx % O;
    int t  = idx / O;
    int oy = t % O;
    int z  = t / O;
    const float* p = Bin + (size_t)z * IMG * O + (size_t)(oy * s) * O + ox;
    float acc = 0.f;
    for (int j = 0; j < k; ++j) acc += p[(size_t)j * 2 * O];
    Bout[idx] = acc;
}

__global__ void pass_z(const float* __restrict__ Bin, float* __restrict__ Bout,
                       int O, int s, int k, int n2, int n3) {
    int idx = blockIdx.x * blockDim.x + threadIdx.x;
    if (idx >= n3) return;
    int ox = idx % O;
    int t  = idx / O;
    int oy = t % O;
    int oz = t / O;
    const float* p = Bin + (size_t)(oz * s) * O * O + (size_t)oy * O + ox;
    float acc = 0.f;
    for (int l = 0; l < k; ++l) acc += p[(size_t)l * 2 * O * O];
    Bout[idx] = acc;
}

__global__ void reduce_one(const float* __restrict__ B3, int n3, float inv_numel,
                           float wdiv, float* __restrict__ partials) {
    float local = 0.f;
    for (int i = blockIdx.x * 256 + threadIdx.x; i < n3; i += gridDim.x * 256) {
        float i_s = B3[i];
        float t_s = B3[(size_t)n3 + i];
        float i2  = B3[2 * (size_t)n3 + i];
        float t2  = B3[3 * (size_t)n3 + i];
        float it  = B3[4 * (size_t)n3 + i];
        local += wdiv * lncc1(i_s, t_s, i2, t2, it, inv_numel);
    }
    __shared__ float red[256];
    red[threadIdx.x] = local;
    __syncthreads();
    for (int o = 128; o > 0; o >>= 1) {
        if (threadIdx.x < o) red[threadIdx.x] += red[threadIdx.x + o];
        __syncthreads();
    }
    if (threadIdx.x == 0) partials[blockIdx.x] += red[0];
}

__global__ void zero_buf(float* __restrict__ p, int n) {
    int i = blockIdx.x * 256 + threadIdx.x;
    if (i < n) p[i] = 0.f;
}

// ---------------------------------------------------------------------------
extern "C" void kernel_launch(void* const* d_in, const int* in_sizes, int n_in,
                              void* d_out, int out_size, void* d_ws, size_t ws_size,
                              hipStream_t stream) {
    const float* I = (const float*)d_in[0];
    const float* T = (const float*)d_in[1];
    float* out = (float*)d_out;
    float* ws  = (float*)d_ws;

    const size_t szB2 = 3283200;
    const size_t szB3 = 974700;
    const size_t need = (szB2 + szB3 + 1024) * sizeof(float);   // ~17 MB

    if (ws_size >= need) {
        float* B2 = ws;
        float* B3 = B2 + szB2;
        float* partials = B3 + szB3;
        fuseXY_s0<<<192 * 8, 256, 0, stream>>>(I, T, B2);
        passZ_s0<<<952, 256, 0, stream>>>(B2, (float4*)B3);
        reduce_all<<<256, 256, 0, stream>>>(B3, partials);
        finalize_n<<<1, 256, 0, stream>>>(partials, 256, out);
    } else {
        // minimal-ws path: per scale, per channel pipelines (scalar, unpadded)
        const int   Ks[3] = {12, 24, 48};
        const int   Ss[3] = {3, 6, 12};
        const int   Os[3] = {57, 25, 9};
        const int   N1[3] = {2101248, 921600, 331776};
        const int   N2[3] = {623808, 120000, 15552};
        const int   N3[3] = {185193, 15625, 729};
        const float Wt[3] = {0.1f, 0.3f, 0.6f};

        float* B1 = ws;                 // n1_max = 2101248
        float* B2 = B1 + 2101248;       // n2_max = 623808
        float* B3 = B2 + 623808;        // 5 * n3_max = 925965
        float* partials = B3 + 925965;  // 256

        zero_buf<<<1, 256, 0, stream>>>(partials, 256);
        for (int sc = 0; sc < 3; ++sc) {
            int k = Ks[sc], s = Ss[sc], O = Os[sc];
            int n1 = N1[sc], n2 = N2[sc], n3 = N3[sc];
            for (int c = 0; c < 5; ++c) {
                pass1_one<<<(n1 + 255) / 256, 256, 0, stream>>>(I, T, B1, O, s, k, c);
                pass_y<<<(n2 + 255) / 256, 256, 0, stream>>>(B1, B2, O, s, k, n1, n2);
                pass_z<<<(n3 + 255) / 256, 256, 0, stream>>>(B2, B3 + (size_t)c * n3, O, s, k, n2, n3);
            }
            int nblk = (n3 + 255) / 256; if (nblk > 256) nblk = 256;
            reduce_one<<<nblk, 256, 0, stream>>>(B3, n3, 1.f / ((float)k * k * k),
                                                 Wt[sc] / (float)n3, partials);
        }
        finalize_n<<<1, 256, 0, stream>>>(partials, 256, out);
    }
}

// Round 9
// 62.478 us; speedup vs baseline: 1.1105x; 1.1105x over previous
//
#include <hip/hip_runtime.h>

#define IMG 192
// B1: [5][zy=36864][60] = 11,059,200 fl (44.2 MB), channel stride CS1=2211840
// B2: [5][z=192][oy=57][60] = 3,283,200 fl (13.1 MB)
// B3: [5][oz=57][oy=57][60] =   974,700 fl (3.9 MB)
// partials[256]: [0,191) scale0 (passZ_red0), [191,256) scales 1/2 (red12).

// ---------------------------------------------------------------------------
// Pass 1 (x): 16 rows/block staged in LDS, 4 outputs/thread, float4 stores.
// Outputs ox=4g..4g+3 share the 33-float window lds[g*12 .. g*12+32].
// Bank pattern: (8*row + 12*g + i) mod 32 -> worst 2-way (free).
// ---------------------------------------------------------------------------
__global__ __launch_bounds__(256) void pass1_s0(
    const float* __restrict__ I, const float* __restrict__ T,
    float* __restrict__ B1)
{
    __shared__ float lI[16][200];
    __shared__ float lT[16][200];
    const int tid = threadIdx.x;
    const int r0  = blockIdx.x * 16;

    const float4* I4 = (const float4*)(I + (size_t)r0 * IMG);
    const float4* T4 = (const float4*)(T + (size_t)r0 * IMG);
    for (int t = tid; t < 16 * 48; t += 256) {
        int row = t / 48, x4 = t - row * 48;
        ((float4*)&lI[row][0])[x4] = I4[t];
        ((float4*)&lT[row][0])[x4] = T4[t];
    }
    if (tid < 32) {
        int row = tid >> 1, h = tid & 1;
        ((float4*)&lI[row][0])[48 + h] = make_float4(0.f, 0.f, 0.f, 0.f);
    } else if (tid < 64) {
        int row = (tid - 32) >> 1, h = tid & 1;
        ((float4*)&lT[row][0])[48 + h] = make_float4(0.f, 0.f, 0.f, 0.f);
    }
    __syncthreads();

    const int row = tid >> 4;      // 0..15
    const int g   = tid & 15;      // 0..15, active g<15
    if (g < 15) {
        const float* a = &lI[row][g * 12];
        const float* b = &lT[row][g * 12];
        float oI[4], oT[4], oI2[4], oT2[4], oIT[4];
#pragma unroll
        for (int j = 0; j < 4; ++j) {
            float sI = 0.f, sT = 0.f, sI2 = 0.f, sT2 = 0.f, sIT = 0.f;
#pragma unroll
            for (int i = 0; i < 12; ++i) {
                float x = a[3 * j + 2 * i], y = b[3 * j + 2 * i];
                sI += x; sT += y; sI2 += x * x; sT2 += y * y; sIT += x * y;
            }
            oI[j] = sI; oT[j] = sT; oI2[j] = sI2; oT2[j] = sT2; oIT[j] = sIT;
        }
        float4* B = (float4*)B1;
        constexpr size_t C4 = 552960;            // CS1/4
        size_t o = (size_t)(r0 + row) * 15 + g;
        B[o]           = make_float4(oI[0], oI[1], oI[2], oI[3]);
        B[C4 + o]      = make_float4(oT[0], oT[1], oT[2], oT[3]);
        B[2 * C4 + o]  = make_float4(oI2[0], oI2[1], oI2[2], oI2[3]);
        B[3 * C4 + o]  = make_float4(oT2[0], oT2[1], oT2[2], oT2[3]);
        B[4 * C4 + o]  = make_float4(oIT[0], oIT[1], oIT[2], oIT[3]);
    }
}

// ---------------------------------------------------------------------------
// Pass 2 (y), float4: B1[c][z*192+3oy+2j][60] -> B2[c][z][oy][60].
// ---------------------------------------------------------------------------
__global__ __launch_bounds__(256) void passY_s0(
    const float* __restrict__ B1, float4* __restrict__ B2)
{
    constexpr int POV = 15;
    constexpr int CV  = IMG * 57 * POV;
    constexpr size_t CS1 = 2211840;
    int idx = blockIdx.x * 256 + threadIdx.x;
    if (idx >= 5 * CV) return;
    int c   = idx / CV;
    int r   = idx - c * CV;
    int ox4 = r % POV;
    int t   = r / POV;
    int oy  = t % 57;
    int z   = t / 57;
    const float4* p = (const float4*)(B1 + c * CS1
                       + ((size_t)z * IMG + (size_t)oy * 3) * 60) + ox4;
    float4 acc = make_float4(0.f, 0.f, 0.f, 0.f);
#pragma unroll
    for (int j = 0; j < 12; ++j) {
        float4 v = p[(size_t)j * 2 * POV];
        acc.x += v.x; acc.y += v.y; acc.z += v.z; acc.w += v.w;
    }
    B2[idx] = acc;
}

// ---------------------------------------------------------------------------
__device__ __forceinline__ float lncc1(float i_s, float t_s, float i2, float t2,
                                       float it, float inv_numel) {
    float cross = it - i_s * t_s * inv_numel;
    float iv    = i2 - i_s * i_s * inv_numel;
    float tv    = t2 - t_s * t_s * inv_numel;
    return cross * cross / (iv * tv + 1e-5f);
}

// ---------------------------------------------------------------------------
// Pass 3 (z) + scale0 LNCC + partial reduce. One thread per float4 of B3.
// ---------------------------------------------------------------------------
__global__ __launch_bounds__(256) void passZ_red0(
    const float* __restrict__ B2, float* __restrict__ B3,
    float* __restrict__ partials)
{
    constexpr int POV = 15;
    constexpr int CV  = IMG * 57 * POV;     // 164160 f4/channel
    constexpr int N3V = 57 * 57 * POV;      // 48735 f4/channel
    int rv = blockIdx.x * 256 + threadIdx.x;
    float local = 0.f;
    if (rv < N3V) {
        int ox4 = rv % POV;
        int t   = rv / POV;
        int oy  = t % 57;
        int oz  = t / 57;
        const float4* base = (const float4*)B2
            + (size_t)(oz * 3) * 57 * POV + (size_t)oy * POV + ox4;
        float4 s0 = make_float4(0,0,0,0), s1 = s0, s2 = s0, s3 = s0, s4 = s0;
#pragma unroll 4
        for (int l = 0; l < 12; ++l) {
            size_t off = (size_t)l * 2 * 57 * POV;
            float4 v0 = base[off];
            float4 v1 = base[(size_t)1 * CV + off];
            float4 v2 = base[(size_t)2 * CV + off];
            float4 v3 = base[(size_t)3 * CV + off];
            float4 v4 = base[(size_t)4 * CV + off];
            s0.x += v0.x; s0.y += v0.y; s0.z += v0.z; s0.w += v0.w;
            s1.x += v1.x; s1.y += v1.y; s1.z += v1.z; s1.w += v1.w;
            s2.x += v2.x; s2.y += v2.y; s2.z += v2.z; s2.w += v2.w;
            s3.x += v3.x; s3.y += v3.y; s3.z += v3.z; s3.w += v3.w;
            s4.x += v4.x; s4.y += v4.y; s4.z += v4.z; s4.w += v4.w;
        }
        float4* B3v = (float4*)B3;
        B3v[rv]                    = s0;
        B3v[(size_t)1 * N3V + rv]  = s1;
        B3v[(size_t)2 * N3V + rv]  = s2;
        B3v[(size_t)3 * N3V + rv]  = s3;
        B3v[(size_t)4 * N3V + rv]  = s4;
        const float inv_numel = 1.f / 1728.f;
        int ox = ox4 * 4;
        if (ox + 0 < 57) local += lncc1(s0.x, s1.x, s2.x, s3.x, s4.x, inv_numel);
        if (ox + 1 < 57) local += lncc1(s0.y, s1.y, s2.y, s3.y, s4.y, inv_numel);
        if (ox + 2 < 57) local += lncc1(s0.z, s1.z, s2.z, s3.z, s4.z, inv_numel);
        if (ox + 3 < 57) local += lncc1(s0.w, s1.w, s2.w, s3.w, s4.w, inv_numel);
        local *= 0.1f / 185193.f;
    }
    __shared__ float red[256];
    red[threadIdx.x] = local;
    __syncthreads();
    for (int o = 128; o > 0; o >>= 1) {
        if (threadIdx.x < o) red[threadIdx.x] += red[threadIdx.x + o];
        __syncthreads();
    }
    if (threadIdx.x == 0) partials[blockIdx.x] = red[0];
}

// ---------------------------------------------------------------------------
// Scales 1/2 from B3 (nested-window decomposition) -> partials[191..255].
// ---------------------------------------------------------------------------
template<int DN, int M>
__device__ __forceinline__ float derive_lncc(const float* __restrict__ B3,
                                             int r, int O1,
                                             float inv_numel, float wdiv) {
    int ox = r % O1;
    int t  = r / O1;
    int oy = t % O1;
    int oz = t / O1;
    float s[5];
    for (int c = 0; c < 5; ++c) {
        float acc = 0.f;
        for (int iz = 0; iz < DN; ++iz)
            for (int iy = 0; iy < DN; ++iy) {
                const float* p = B3
                    + (((size_t)c * 57 + (M * oz + 8 * iz)) * 57
                       + (M * oy + 8 * iy)) * 60 + M * ox;
#pragma unroll
                for (int ix = 0; ix < DN; ++ix) acc += p[8 * ix];
            }
        s[c] = acc;
    }
    return wdiv * lncc1(s[0], s[1], s[2], s[3], s[4], inv_numel);
}

__global__ __launch_bounds__(256) void red12(
    const float* __restrict__ B3, float* __restrict__ partials)
{
    const int b = blockIdx.x;
    float v = 0.f;
    if (b < 62) {                                    // scale1: 15625 outputs
        int r = b * 256 + threadIdx.x;
        if (r < 15625)
            v = derive_lncc<2, 2>(B3, r, 25, 1.f / 13824.f, 0.3f / 15625.f);
    } else {                                         // scale2: 729 outputs
        int r = (b - 62) * 256 + threadIdx.x;
        if (r < 729)
            v = derive_lncc<4, 4>(B3, r, 9, 1.f / 110592.f, 0.6f / 729.f);
    }
    __shared__ float red[256];
    red[threadIdx.x] = v;
    __syncthreads();
    for (int o = 128; o > 0; o >>= 1) {
        if (threadIdx.x < o) red[threadIdx.x] += red[threadIdx.x + o];
        __syncthreads();
    }
    if (threadIdx.x == 0) partials[191 + blockIdx.x] = red[0];
}

__global__ __launch_bounds__(256) void finalize_n(
    const float* __restrict__ partials, int n, float* __restrict__ out)
{
    float v = 0.f;
    for (int i = threadIdx.x; i < n; i += 256) v += partials[i];
    __shared__ float red[256];
    red[threadIdx.x] = v;
    __syncthreads();
    for (int o = 128; o > 0; o >>= 1) {
        if (threadIdx.x < o) red[threadIdx.x] += red[threadIdx.x + o];
        __syncthreads();
    }
    if (threadIdx.x == 0) out[0] = 1.0f - red[0];
}

// ------------------- fallback kernels (small-ws path) ----------------------
__global__ void pass1_one(const float* __restrict__ I, const float* __restrict__ T,
                          float* __restrict__ B1, int O, int s, int k, int c) {
    int idx = blockIdx.x * blockDim.x + threadIdx.x;
    if (idx >= IMG * IMG * O) return;
    int ox = idx % O;
    int zy = idx / O;
    const float* pI = I + (size_t)zy * IMG + ox * s;
    const float* pT = T + (size_t)zy * IMG + ox * s;
    float acc = 0.f;
    for (int i = 0; i < k; ++i) {
        float v;
        if (c == 0)      v = pI[2 * i];
        else if (c == 1) v = pT[2 * i];
        else if (c == 2) { float a = pI[2 * i]; v = a * a; }
        else if (c == 3) { float bb = pT[2 * i]; v = bb * bb; }
        else             { v = pI[2 * i] * pT[2 * i]; }
        acc += v;
    }
    B1[idx] = acc;
}

__global__ void pass_y(const float* __restrict__ Bin, float* __restrict__ Bout,
                       int O, int s, int k, int n1, int n2) {
    int idx = blockIdx.x * blockDim.x + threadIdx.x;
    if (idx >= n2) return;
    int ox = idx % O;
    int t  = idx / O;
    int oy = t % O;
    int z  = t / O;
    const float* p = Bin + (size_t)z * IMG * O + (size_t)(oy * s) * O + ox;
    float acc = 0.f;
    for (int j = 0; j < k; ++j) acc += p[(size_t)j * 2 * O];
    Bout[idx] = acc;
}

__global__ void pass_z(const float* __restrict__ Bin, float* __restrict__ Bout,
                       int O, int s, int k, int n2, int n3) {
    int idx = blockIdx.x * blockDim.x + threadIdx.x;
    if (idx >= n3) return;
    int ox = idx % O;
    int t  = idx / O;
    int oy = t % O;
    int oz = t / O;
    const float* p = Bin + (size_t)(oz * s) * O * O + (size_t)oy * O + ox;
    float acc = 0.f;
    for (int l = 0; l < k; ++l) acc += p[(size_t)l * 2 * O * O];
    Bout[idx] = acc;
}

__global__ void reduce_one(const float* __restrict__ B3, int n3, float inv_numel,
                           float wdiv, float* __restrict__ partials) {
    float local = 0.f;
    for (int i = blockIdx.x * 256 + threadIdx.x; i < n3; i += gridDim.x * 256) {
        float i_s = B3[i];
        float t_s = B3[(size_t)n3 + i];
        float i2  = B3[2 * (size_t)n3 + i];
        float t2  = B3[3 * (size_t)n3 + i];
        float it  = B3[4 * (size_t)n3 + i];
        local += wdiv * lncc1(i_s, t_s, i2, t2, it, inv_numel);
    }
    __shared__ float red[256];
    red[threadIdx.x] = local;
    __syncthreads();
    for (int o = 128; o > 0; o >>= 1) {
        if (threadIdx.x < o) red[threadIdx.x] += red[threadIdx.x + o];
        __syncthreads();
    }
    if (threadIdx.x == 0) partials[blockIdx.x] += red[0];
}

__global__ void zero_buf(float* __restrict__ p, int n) {
    int i = blockIdx.x * 256 + threadIdx.x;
    if (i < n) p[i] = 0.f;
}

// ---------------------------------------------------------------------------
extern "C" void kernel_launch(void* const* d_in, const int* in_sizes, int n_in,
                              void* d_out, int out_size, void* d_ws, size_t ws_size,
                              hipStream_t stream) {
    const float* I = (const float*)d_in[0];
    const float* T = (const float*)d_in[1];
    float* out = (float*)d_out;
    float* ws  = (float*)d_ws;

    const size_t szB1 = 11059200;
    const size_t szB2 = 3283200;
    const size_t szB3 = 974700;
    const size_t need = (szB1 + szB2 + szB3 + 1024) * sizeof(float);  // ~61 MB

    if (ws_size >= need) {
        float* B1 = ws;
        float* B2 = B1 + szB1;
        float* B3 = B2 + szB2;
        float* partials = B3 + szB3;
        pass1_s0<<<2304, 256, 0, stream>>>(I, T, B1);
        passY_s0<<<3207, 256, 0, stream>>>(B1, (float4*)B2);
        passZ_red0<<<191, 256, 0, stream>>>(B2, B3, partials);
        red12<<<65, 256, 0, stream>>>(B3, partials);
        finalize_n<<<1, 256, 0, stream>>>(partials, 256, out);
    } else {
        const int   Ks[3] = {12, 24, 48};
        const int   Ss[3] = {3, 6, 12};
        const int   Os[3] = {57, 25, 9};
        const int   N1[3] = {2101248, 921600, 331776};
        const int   N2[3] = {623808, 120000, 15552};
        const int   N3[3] = {185193, 15625, 729};
        const float Wt[3] = {0.1f, 0.3f, 0.6f};

        float* B1 = ws;
        float* B2 = B1 + 2101248;
        float* B3 = B2 + 623808;
        float* partials = B3 + 925965;

        zero_buf<<<1, 256, 0, stream>>>(partials, 256);
        for (int sc = 0; sc < 3; ++sc) {
            int k = Ks[sc], s = Ss[sc], O = Os[sc];
            int n1 = N1[sc], n2 = N2[sc], n3 = N3[sc];
            for (int c = 0; c < 5; ++c) {
                pass1_one<<<(n1 + 255) / 256, 256, 0, stream>>>(I, T, B1, O, s, k, c);
                pass_y<<<(n2 + 255) / 256, 256, 0, stream>>>(B1, B2, O, s, k, n1, n2);
                pass_z<<<(n3 + 255) / 256, 256, 0, stream>>>(B2, B3 + (size_t)c * n3, O, s, k, n2, n3);
            }
            int nblk = (n3 + 255) / 256; if (nblk > 256) nblk = 256;
            reduce_one<<<nblk, 256, 0, stream>>>(B3, n3, 1.f / ((float)k * k * k),
                                                 Wt[sc] / (float)n3, partials);
        }
        finalize_n<<<1, 256, 0, stream>>>(partials, 256, out);
    }
}

// Round 10
// 55.825 us; speedup vs baseline: 1.2429x; 1.1192x over previous
//
#include <hip/hip_runtime.h>
#include <hip/hip_fp16.h>

#define IMG 192
#define ROWP 196      // LDS row stride (floats); 196 mod 32 = 4, reads use 3*ox spread
#define CS1H 2211840  // B1h halves per channel = 36864*60
// B1h: [5][zy=36864][60] halves = 22.1 MB
// B2h: [5][z=192][oy=57][60] halves = 6.6 MB
// B3 : [5][oz=57][oy=57][60] fp32  = 3.9 MB
// partials[256]: [0,191) scale0 (passZ_red0), [191,256) scales 1/2 (red12).

__device__ __forceinline__ float2 h2f(unsigned int u) {
    __half2 h = *reinterpret_cast<const __half2*>(&u);
    return __half22float2(h);
}
__device__ __forceinline__ unsigned int f2h(float a, float b) {
    __half2 h = __floats2half2_rn(a, b);
    return *reinterpret_cast<const unsigned int*>(&h);
}

// ---------------------------------------------------------------------------
// Pass 1 (x): R7 structure (8 rows/block, 1 output/thread, conflict-free LDS
// reads at stride 3*ox), fp16 stores.
// ---------------------------------------------------------------------------
__global__ __launch_bounds__(256) void pass1_s0(
    const float* __restrict__ I, const float* __restrict__ T,
    __half* __restrict__ B1h)
{
    __shared__ float lI[8 * ROWP];
    __shared__ float lT[8 * ROWP];
    const int tid = threadIdx.x;
    const int r0  = blockIdx.x * 8;

    const float4* I4 = (const float4*)(I + (size_t)r0 * IMG);
    const float4* T4 = (const float4*)(T + (size_t)r0 * IMG);
    float4* lI4 = (float4*)lI;
    float4* lT4 = (float4*)lT;
    for (int t = tid; t < 8 * 48; t += 256) {
        int row = t / 48, xi = t - row * 48;
        lI4[row * (ROWP / 4) + xi] = I4[t];
        lT4[row * (ROWP / 4) + xi] = T4[t];
    }
    __syncthreads();

    for (int w = tid; w < 8 * 57; w += 256) {
        int row = w / 57, ox = w - row * 57;
        const float* a = &lI[row * ROWP + ox * 3];
        const float* b = &lT[row * ROWP + ox * 3];
        float sI = 0.f, sT = 0.f, sI2 = 0.f, sT2 = 0.f, sIT = 0.f;
#pragma unroll
        for (int i = 0; i < 12; ++i) {
            float x = a[2 * i], y = b[2 * i];
            sI += x; sT += y; sI2 += x * x; sT2 += y * y; sIT += x * y;
        }
        size_t o = (size_t)(r0 + row) * 60 + ox;
        B1h[o]             = __float2half_rn(sI);
        B1h[CS1H + o]      = __float2half_rn(sT);
        B1h[2 * CS1H + o]  = __float2half_rn(sI2);
        B1h[3 * CS1H + o]  = __float2half_rn(sT2);
        B1h[4 * CS1H + o]  = __float2half_rn(sIT);
    }
}

// ---------------------------------------------------------------------------
// Pass 2 (y): half4 in (uint2), fp32 accumulate, half4 out.
// B2h layout [c][z][oy][60] halves; write index == idx (uint2 granules).
// ---------------------------------------------------------------------------
__global__ __launch_bounds__(256) void passY_s0(
    const __half* __restrict__ B1h, uint2* __restrict__ B2h)
{
    constexpr int POV = 15;                 // groups of 4 halves
    constexpr int CV  = IMG * 57 * POV;     // 164160 per channel
    int idx = blockIdx.x * 256 + threadIdx.x;
    if (idx >= 5 * CV) return;
    int c   = idx / CV;
    int r   = idx - c * CV;
    int ox4 = r % POV;
    int t   = r / POV;
    int oy  = t % 57;
    int z   = t / 57;
    const uint2* p = (const uint2*)(B1h + (size_t)c * CS1H
                      + ((size_t)z * IMG + (size_t)oy * 3) * 60) + ox4;
    float4 acc = make_float4(0.f, 0.f, 0.f, 0.f);
#pragma unroll
    for (int j = 0; j < 12; ++j) {
        uint2 u = p[(size_t)j * 2 * POV];
        float2 f0 = h2f(u.x), f1 = h2f(u.y);
        acc.x += f0.x; acc.y += f0.y; acc.z += f1.x; acc.w += f1.y;
    }
    uint2 o;
    o.x = f2h(acc.x, acc.y);
    o.y = f2h(acc.z, acc.w);
    B2h[idx] = o;
}

// ---------------------------------------------------------------------------
__device__ __forceinline__ float lncc1(float i_s, float t_s, float i2, float t2,
                                       float it, float inv_numel) {
    float cross = it - i_s * t_s * inv_numel;
    float iv    = i2 - i_s * i_s * inv_numel;
    float tv    = t2 - t_s * t_s * inv_numel;
    return cross * cross / (iv * tv + 1e-5f);
}

// ---------------------------------------------------------------------------
// Pass 3 (z) + scale0 LNCC + partial reduce; also zeroes red12's counter.
// ---------------------------------------------------------------------------
__global__ __launch_bounds__(256) void passZ_red0(
    const uint2* __restrict__ B2h, float* __restrict__ B3,
    float* __restrict__ partials, unsigned int* __restrict__ counter)
{
    constexpr int POV = 15;
    constexpr int CV  = IMG * 57 * POV;     // uint2 per channel
    constexpr int N3V = 57 * 57 * POV;      // f4 per channel of B3
    int rv = blockIdx.x * 256 + threadIdx.x;
    float local = 0.f;
    if (blockIdx.x == 0 && threadIdx.x == 0) counter[0] = 0u;
    if (rv < N3V) {
        int ox4 = rv % POV;
        int t   = rv / POV;
        int oy  = t % 57;
        int oz  = t / 57;
        const uint2* base = B2h + (size_t)(oz * 3) * 57 * POV
                            + (size_t)oy * POV + ox4;
        float4 s0 = make_float4(0,0,0,0), s1 = s0, s2 = s0, s3 = s0, s4 = s0;
#pragma unroll 4
        for (int l = 0; l < 12; ++l) {
            size_t off = (size_t)l * 2 * 57 * POV;
            uint2 u0 = base[off];
            uint2 u1 = base[(size_t)1 * CV + off];
            uint2 u2 = base[(size_t)2 * CV + off];
            uint2 u3 = base[(size_t)3 * CV + off];
            uint2 u4 = base[(size_t)4 * CV + off];
            float2 a, b;
            a = h2f(u0.x); b = h2f(u0.y); s0.x += a.x; s0.y += a.y; s0.z += b.x; s0.w += b.y;
            a = h2f(u1.x); b = h2f(u1.y); s1.x += a.x; s1.y += a.y; s1.z += b.x; s1.w += b.y;
            a = h2f(u2.x); b = h2f(u2.y); s2.x += a.x; s2.y += a.y; s2.z += b.x; s2.w += b.y;
            a = h2f(u3.x); b = h2f(u3.y); s3.x += a.x; s3.y += a.y; s3.z += b.x; s3.w += b.y;
            a = h2f(u4.x); b = h2f(u4.y); s4.x += a.x; s4.y += a.y; s4.z += b.x; s4.w += b.y;
        }
        float4* B3v = (float4*)B3;
        B3v[rv]                    = s0;
        B3v[(size_t)1 * N3V + rv]  = s1;
        B3v[(size_t)2 * N3V + rv]  = s2;
        B3v[(size_t)3 * N3V + rv]  = s3;
        B3v[(size_t)4 * N3V + rv]  = s4;
        const float inv_numel = 1.f / 1728.f;
        int ox = ox4 * 4;
        if (ox + 0 < 57) local += lncc1(s0.x, s1.x, s2.x, s3.x, s4.x, inv_numel);
        if (ox + 1 < 57) local += lncc1(s0.y, s1.y, s2.y, s3.y, s4.y, inv_numel);
        if (ox + 2 < 57) local += lncc1(s0.z, s1.z, s2.z, s3.z, s4.z, inv_numel);
        if (ox + 3 < 57) local += lncc1(s0.w, s1.w, s2.w, s3.w, s4.w, inv_numel);
        local *= 0.1f / 185193.f;
    }
    __shared__ float red[256];
    red[threadIdx.x] = local;
    __syncthreads();
    for (int o = 128; o > 0; o >>= 1) {
        if (threadIdx.x < o) red[threadIdx.x] += red[threadIdx.x + o];
        __syncthreads();
    }
    if (threadIdx.x == 0) partials[blockIdx.x] = red[0];
}

// ---------------------------------------------------------------------------
// Scales 1/2 from B3 (nested windows) + last-block final sum -> out.
// ---------------------------------------------------------------------------
template<int DN, int M>
__device__ __forceinline__ float derive_lncc(const float* __restrict__ B3,
                                             int r, int O1,
                                             float inv_numel, float wdiv) {
    int ox = r % O1;
    int t  = r / O1;
    int oy = t % O1;
    int oz = t / O1;
    float s[5];
    for (int c = 0; c < 5; ++c) {
        float acc = 0.f;
        for (int iz = 0; iz < DN; ++iz)
            for (int iy = 0; iy < DN; ++iy) {
                const float* p = B3
                    + (((size_t)c * 57 + (M * oz + 8 * iz)) * 57
                       + (M * oy + 8 * iy)) * 60 + M * ox;
#pragma unroll
                for (int ix = 0; ix < DN; ++ix) acc += p[8 * ix];
            }
        s[c] = acc;
    }
    return wdiv * lncc1(s[0], s[1], s[2], s[3], s[4], inv_numel);
}

__global__ __launch_bounds__(256) void red12(
    const float* __restrict__ B3, float* __restrict__ partials,
    unsigned int* __restrict__ counter, float* __restrict__ out)
{
    const int b = blockIdx.x;
    float v = 0.f;
    if (b < 62) {                                    // scale1: 15625 outputs
        int r = b * 256 + threadIdx.x;
        if (r < 15625)
            v = derive_lncc<2, 2>(B3, r, 25, 1.f / 13824.f, 0.3f / 15625.f);
    } else {                                         // scale2: 729 outputs
        int r = (b - 62) * 256 + threadIdx.x;
        if (r < 729)
            v = derive_lncc<4, 4>(B3, r, 9, 1.f / 110592.f, 0.6f / 729.f);
    }
    __shared__ float red[256];
    red[threadIdx.x] = v;
    __syncthreads();
    for (int o = 128; o > 0; o >>= 1) {
        if (threadIdx.x < o) red[threadIdx.x] += red[threadIdx.x + o];
        __syncthreads();
    }
    if (threadIdx.x == 0) partials[191 + b] = red[0];

    // last block finalizes: out = 1 - sum(partials[0..256))
    __threadfence();
    __shared__ unsigned int lastFlag;
    if (threadIdx.x == 0)
        lastFlag = (atomicAdd(counter, 1u) == 64u) ? 1u : 0u;
    __syncthreads();
    if (lastFlag) {
        __threadfence();
        float w = partials[threadIdx.x];
        red[threadIdx.x] = w;
        __syncthreads();
        for (int o = 128; o > 0; o >>= 1) {
            if (threadIdx.x < o) red[threadIdx.x] += red[threadIdx.x + o];
            __syncthreads();
        }
        if (threadIdx.x == 0) out[0] = 1.0f - red[0];
    }
}

__global__ __launch_bounds__(256) void finalize_n(
    const float* __restrict__ partials, int n, float* __restrict__ out)
{
    float v = 0.f;
    for (int i = threadIdx.x; i < n; i += 256) v += partials[i];
    __shared__ float red[256];
    red[threadIdx.x] = v;
    __syncthreads();
    for (int o = 128; o > 0; o >>= 1) {
        if (threadIdx.x < o) red[threadIdx.x] += red[threadIdx.x + o];
        __syncthreads();
    }
    if (threadIdx.x == 0) out[0] = 1.0f - red[0];
}

// ------------------- fallback kernels (small-ws path, fp32) ----------------
__global__ void pass1_one(const float* __restrict__ I, const float* __restrict__ T,
                          float* __restrict__ B1, int O, int s, int k, int c) {
    int idx = blockIdx.x * blockDim.x + threadIdx.x;
    if (idx >= IMG * IMG * O) return;
    int ox = idx % O;
    int zy = idx / O;
    const float* pI = I + (size_t)zy * IMG + ox * s;
    const float* pT = T + (size_t)zy * IMG + ox * s;
    float acc = 0.f;
    for (int i = 0; i < k; ++i) {
        float v;
        if (c == 0)      v = pI[2 * i];
        else if (c == 1) v = pT[2 * i];
        else if (c == 2) { float a = pI[2 * i]; v = a * a; }
        else if (c == 3) { float bb = pT[2 * i]; v = bb * bb; }
        else             { v = pI[2 * i] * pT[2 * i]; }
        acc += v;
    }
    B1[idx] = acc;
}

__global__ void pass_y(const float* __restrict__ Bin, float* __restrict__ Bout,
                       int O, int s, int k, int n1, int n2) {
    int idx = blockIdx.x * blockDim.x + threadIdx.x;
    if (idx >= n2) return;
    int ox = idx % O;
    int t  = idx / O;
    int oy = t % O;
    int z  = t / O;
    const float* p = Bin + (size_t)z * IMG * O + (size_t)(oy * s) * O + ox;
    float acc = 0.f;
    for (int j = 0; j < k; ++j) acc += p[(size_t)j * 2 * O];
    Bout[idx] = acc;
}

__global__ void pass_z(const float* __restrict__ Bin, float* __restrict__ Bout,
                       int O, int s, int k, int n2, int n3) {
    int idx = blockIdx.x * blockDim.x + threadIdx.x;
    if (idx >= n3) return;
    int ox = idx % O;
    int t  = idx / O;
    int oy = t % O;
    int oz = t / O;
    const float* p = Bin + (size_t)(oz * s) * O * O + (size_t)oy * O + ox;
    float acc = 0.f;
    for (int l = 0; l < k; ++l) acc += p[(size_t)l * 2 * O * O];
    Bout[idx] = acc;
}

__global__ void reduce_one(const float* __restrict__ B3, int n3, float inv_numel,
                           float wdiv, float* __restrict__ partials) {
    float local = 0.f;
    for (int i = blockIdx.x * 256 + threadIdx.x; i < n3; i += gridDim.x * 256) {
        float i_s = B3[i];
        float t_s = B3[(size_t)n3 + i];
        float i2  = B3[2 * (size_t)n3 + i];
        float t2  = B3[3 * (size_t)n3 + i];
        float it  = B3[4 * (size_t)n3 + i];
        local += wdiv * lncc1(i_s, t_s, i2, t2, it, inv_numel);
    }
    __shared__ float red[256];
    red[threadIdx.x] = local;
    __syncthreads();
    for (int o = 128; o > 0; o >>= 1) {
        if (threadIdx.x < o) red[threadIdx.x] += red[threadIdx.x + o];
        __syncthreads();
    }
    if (threadIdx.x == 0) partials[blockIdx.x] += red[0];
}

__global__ void zero_buf(float* __restrict__ p, int n) {
    int i = blockIdx.x * 256 + threadIdx.x;
    if (i < n) p[i] = 0.f;
}

// ---------------------------------------------------------------------------
extern "C" void kernel_launch(void* const* d_in, const int* in_sizes, int n_in,
                              void* d_out, int out_size, void* d_ws, size_t ws_size,
                              hipStream_t stream) {
    const float* I = (const float*)d_in[0];
    const float* T = (const float*)d_in[1];
    float* out = (float*)d_out;
    float* ws  = (float*)d_ws;

    const size_t szB1f = 5529600;    // B1h as float-equivalents (22.1 MB)
    const size_t szB2f = 1641600;    // B2h as float-equivalents (6.6 MB)
    const size_t szB3  = 974700;     // fp32
    const size_t need  = (szB1f + szB2f + szB3 + 1024) * sizeof(float); // ~33 MB

    if (ws_size >= need) {
        __half* B1h = (__half*)ws;
        uint2*  B2h = (uint2*)(ws + szB1f);
        float*  B3  = ws + szB1f + szB2f;
        float*  partials = B3 + szB3;
        unsigned int* counter = (unsigned int*)(partials + 256);
        pass1_s0<<<4608, 256, 0, stream>>>(I, T, B1h);
        passY_s0<<<3207, 256, 0, stream>>>(B1h, B2h);
        passZ_red0<<<191, 256, 0, stream>>>(B2h, B3, partials, counter);
        red12<<<65, 256, 0, stream>>>(B3, partials, counter, out);
    } else {
        const int   Ks[3] = {12, 24, 48};
        const int   Ss[3] = {3, 6, 12};
        const int   Os[3] = {57, 25, 9};
        const int   N1[3] = {2101248, 921600, 331776};
        const int   N2[3] = {623808, 120000, 15552};
        const int   N3[3] = {185193, 15625, 729};
        const float Wt[3] = {0.1f, 0.3f, 0.6f};

        float* B1 = ws;
        float* B2 = B1 + 2101248;
        float* B3 = B2 + 623808;
        float* partials = B3 + 925965;

        zero_buf<<<1, 256, 0, stream>>>(partials, 256);
        for (int sc = 0; sc < 3; ++sc) {
            int k = Ks[sc], s = Ss[sc], O = Os[sc];
            int n1 = N1[sc], n2 = N2[sc], n3 = N3[sc];
            for (int c = 0; c < 5; ++c) {
                pass1_one<<<(n1 + 255) / 256, 256, 0, stream>>>(I, T, B1, O, s, k, c);
                pass_y<<<(n2 + 255) / 256, 256, 0, stream>>>(B1, B2, O, s, k, n1, n2);
                pass_z<<<(n3 + 255) / 256, 256, 0, stream>>>(B2, B3 + (size_t)c * n3, O, s, k, n2, n3);
            }
            int nblk = (n3 + 255) / 256; if (nblk > 256) nblk = 256;
            reduce_one<<<nblk, 256, 0, stream>>>(B3, n3, 1.f / ((float)k * k * k),
                                                 Wt[sc] / (float)n3, partials);
        }
        finalize_n<<<1, 256, 0, stream>>>(partials, 256, out);
    }
}